// Round 1
// baseline (3465.360 us; speedup 1.0000x reference)
//
#include <hip/hip_runtime.h>
#include <hip/hip_bf16.h>

#define N_ATOMS 100000
#define N_BONDS 200000
#define MAX_NB 6
#define HIDDEN 300
#define ATOM_FD 133
#define BOND_FD 147
#define N_MOLS 5000
#define APM 20

using bf16 = __hip_bfloat16;

__device__ __forceinline__ float b2f(bf16 v) { return __bfloat162float(v); }
__device__ __forceinline__ bf16 f2b(float v) { return __float2bfloat16(v); }

// K1: inp = f_bonds @ W_i ; msg = relu(inp). 16 bond-rows per block.
__global__ void k1_input(const float* __restrict__ fb, const float* __restrict__ Wi,
                         bf16* __restrict__ inp, bf16* __restrict__ msg) {
    __shared__ float a[16][BOND_FD];
    const int tid = threadIdx.x;
    const long base = (long)blockIdx.x * 16;
    for (int i = tid; i < 16 * BOND_FD; i += 320) {
        int r = i / BOND_FD, c = i % BOND_FD;
        a[r][c] = fb[(base + r) * BOND_FD + c];
    }
    __syncthreads();
    if (tid >= HIDDEN) return;
    float acc[16];
#pragma unroll
    for (int r = 0; r < 16; ++r) acc[r] = 0.f;
    for (int k = 0; k < BOND_FD; ++k) {
        float w = Wi[k * HIDDEN + tid];
#pragma unroll
        for (int r = 0; r < 16; ++r) acc[r] += a[r][k] * w;
    }
#pragma unroll
    for (int r = 0; r < 16; ++r) {
        float v = acc[r];
        inp[(base + r) * HIDDEN + tid] = f2b(v);
        msg[(base + r) * HIDDEN + tid] = f2b(fmaxf(v, 0.f));
    }
}

// K2: amsg[a] = sum_j msg[a2b[a][j]]  (padded-neighbor gather-sum)
__global__ void k2_gather(const bf16* __restrict__ msg, const int* __restrict__ a2b,
                          bf16* __restrict__ amsg) {
    const int a = blockIdx.x;
    const int tid = threadIdx.x;
    if (tid >= HIDDEN) return;
    float s = 0.f;
#pragma unroll
    for (int j = 0; j < MAX_NB; ++j) {
        int b = a2b[a * MAX_NB + j];
        s += b2f(msg[(long)b * HIDDEN + tid]);
    }
    amsg[(long)a * HIDDEN + tid] = f2b(s);
}

// K3: newmsg = relu(inp + (amsg[b2a] - msg[b2revb]) @ W_h). 16 bond-rows/block,
// m-row built on the fly into LDS (fused gather).
__global__ void k3_update(const bf16* __restrict__ inp, const bf16* __restrict__ msg,
                          const bf16* __restrict__ amsg, const int* __restrict__ b2a,
                          const int* __restrict__ b2revb, const float* __restrict__ Wh,
                          bf16* __restrict__ outmsg) {
    __shared__ float m[16][HIDDEN];
    const int tid = threadIdx.x;
    const long base = (long)blockIdx.x * 16;
    for (int i = tid; i < 16 * HIDDEN; i += 320) {
        int r = i / HIDDEN, c = i % HIDDEN;
        long b = base + r;
        float am = b2f(amsg[(long)b2a[b] * HIDDEN + c]);
        float rv = b2f(msg[(long)b2revb[b] * HIDDEN + c]);
        m[r][c] = am - rv;
    }
    __syncthreads();
    if (tid >= HIDDEN) return;
    float acc[16];
#pragma unroll
    for (int r = 0; r < 16; ++r) acc[r] = 0.f;
    for (int k = 0; k < HIDDEN; ++k) {
        float w = Wh[k * HIDDEN + tid];
#pragma unroll
        for (int r = 0; r < 16; ++r) acc[r] += m[r][k] * w;
    }
#pragma unroll
    for (int r = 0; r < 16; ++r) {
        long b = base + r;
        float v = b2f(inp[b * HIDDEN + tid]) + acc[r];
        outmsg[b * HIDDEN + tid] = f2b(fmaxf(v, 0.f));
    }
}

// K4: per-molecule readout. atom_hiddens = relu([f_atoms, amsg] @ W_o + b_o),
// mean over the molecule's 20 contiguous atoms. 10 atoms register-blocked.
__global__ void k4_readout(const float* __restrict__ fa, const bf16* __restrict__ amsg,
                           const float* __restrict__ Wo, const float* __restrict__ bo,
                           float* __restrict__ out) {
    __shared__ float ai[10][ATOM_FD + HIDDEN];
    const int tid = threadIdx.x;
    const int mol = blockIdx.x;
    float sum = 0.f;
    for (int c = 0; c < 2; ++c) {
        const int abase = mol * APM + c * 10;
        for (int i = tid; i < 10 * (ATOM_FD + HIDDEN); i += 320) {
            int r = i / (ATOM_FD + HIDDEN), k = i % (ATOM_FD + HIDDEN);
            long a = abase + r;
            float v = (k < ATOM_FD) ? fa[a * ATOM_FD + k]
                                    : b2f(amsg[a * HIDDEN + (k - ATOM_FD)]);
            ai[r][k] = v;
        }
        __syncthreads();
        if (tid < HIDDEN) {
            float acc[10];
#pragma unroll
            for (int r = 0; r < 10; ++r) acc[r] = bo[tid];
            for (int k = 0; k < ATOM_FD + HIDDEN; ++k) {
                float w = Wo[k * HIDDEN + tid];
#pragma unroll
                for (int r = 0; r < 10; ++r) acc[r] += ai[r][k] * w;
            }
#pragma unroll
            for (int r = 0; r < 10; ++r) sum += fmaxf(acc[r], 0.f);
        }
        __syncthreads();
    }
    if (tid < HIDDEN) out[(long)mol * HIDDEN + tid] = sum * (1.f / APM);
}

extern "C" void kernel_launch(void* const* d_in, const int* in_sizes, int n_in,
                              void* d_out, int out_size, void* d_ws, size_t ws_size,
                              hipStream_t stream) {
    const float* f_atoms = (const float*)d_in[0];
    const float* f_bonds = (const float*)d_in[1];
    const int* a2b = (const int*)d_in[2];
    const int* b2a = (const int*)d_in[3];
    const int* b2revb = (const int*)d_in[4];
    // d_in[5] mol_ids: contiguous 20-atom scopes, implied by block index in k4
    const float* Wi = (const float*)d_in[6];
    const float* Wh = (const float*)d_in[7];
    const float* Wo = (const float*)d_in[8];
    const float* bo = (const float*)d_in[9];
    float* out = (float*)d_out;

    char* ws = (char*)d_ws;
    size_t off = 0;
    auto alloc = [&](size_t bytes) {
        void* p = ws + off;
        off = (off + bytes + 255) & ~(size_t)255;
        return p;
    };
    bf16* inp  = (bf16*)alloc((size_t)N_BONDS * HIDDEN * sizeof(bf16));
    bf16* msgA = (bf16*)alloc((size_t)N_BONDS * HIDDEN * sizeof(bf16));
    bf16* msgB = (bf16*)alloc((size_t)N_BONDS * HIDDEN * sizeof(bf16));
    bf16* amsg = (bf16*)alloc((size_t)N_ATOMS * HIDDEN * sizeof(bf16));

    dim3 blk(320);

    // inp = f_bonds @ W_i ; msg0 = relu(inp)
    k1_input<<<N_BONDS / 16, blk, 0, stream>>>(f_bonds, Wi, inp, msgA);

    // depth iteration 1
    k2_gather<<<N_ATOMS, blk, 0, stream>>>(msgA, a2b, amsg);
    k3_update<<<N_BONDS / 16, blk, 0, stream>>>(inp, msgA, amsg, b2a, b2revb, Wh, msgB);

    // depth iteration 2
    k2_gather<<<N_ATOMS, blk, 0, stream>>>(msgB, a2b, amsg);
    k3_update<<<N_BONDS / 16, blk, 0, stream>>>(inp, msgB, amsg, b2a, b2revb, Wh, msgA);

    // readout
    k2_gather<<<N_ATOMS, blk, 0, stream>>>(msgA, a2b, amsg);
    k4_readout<<<N_MOLS, blk, 0, stream>>>(f_atoms, amsg, Wo, bo, out);
}

// Round 2
// 1800.996 us; speedup vs baseline: 1.9241x; 1.9241x over previous
//
#include <hip/hip_runtime.h>
#include <hip/hip_bf16.h>

#define N_ATOMS 100000
#define N_BONDS 200000
#define MAX_NB 6
#define HIDDEN 300
#define ATOM_FD 133
#define BOND_FD 147
#define N_MOLS 5000
#define APM 20

#define NT_H 19              // 19 * 16 = 304 >= 300 output tiles
#define KK_I 5               // K=160 >= 147
#define KK_H 10              // K=320 >= 300
#define KK_O 14              // K=448 >= 433

using bf16 = __hip_bfloat16;
typedef __attribute__((ext_vector_type(8))) short short8v;
typedef __attribute__((ext_vector_type(4))) float float4v;
typedef unsigned int u32;
typedef unsigned short u16;

__device__ __forceinline__ float us2f(u16 u) {
    union { u32 i; float f; } v; v.i = ((u32)u) << 16; return v.f;
}
__device__ __forceinline__ u16 f2us(float f) {
    bf16 h = __float2bfloat16(f);
    return *(u16*)&h;
}
__device__ __forceinline__ u32 pack2(float a, float b) {
    return (u32)f2us(a) | ((u32)f2us(b) << 16);
}

// ---------------------------------------------------------------------------
// pack_w: W [Ksrc x 300] fp32 -> bf16 MFMA-B fragments [KK][19][64 lanes][8]
// lane slot (hi=lane>>4, j) holds W[kk*32 + hi*8 + j][nt*16 + (lane&15)].
// mode==2 (W_o): source row permuted so LDS cols are [amsg(300) | f_atoms(133)].
__global__ __launch_bounds__(64) void pack_w(const float* __restrict__ src,
                                             short* __restrict__ dst,
                                             int Ksrc, int mode) {
    int kk = blockIdx.x / NT_H, nt = blockIdx.x % NT_H;
    int lane = threadIdx.x;
    int col = nt * 16 + (lane & 15);
#pragma unroll
    for (int j = 0; j < 8; ++j) {
        int k = kk * 32 + (lane >> 4) * 8 + j;
        float v = 0.f;
        if (k < Ksrc && col < HIDDEN) {
            int krow = k;
            if (mode == 2) krow = (k < HIDDEN) ? (ATOM_FD + k) : (k - HIDDEN);
            v = src[krow * HIDDEN + col];
        }
        dst[(((kk * NT_H + nt) << 6) + lane) * 8 + j] = (short)f2us(v);
    }
}

// ---------------------------------------------------------------------------
// K1: inp = f_bonds @ W_i ; msg = relu(inp).  64 bond rows / block (4 waves).
__global__ __launch_bounds__(256) void k1_input(const float* __restrict__ fb,
                                                const short8v* __restrict__ WiP,
                                                u16* __restrict__ inp,
                                                u16* __restrict__ msg) {
    __shared__ char sm[64 * 320];            // [64 rows][160 bf16], swizzled
    const int tid = threadIdx.x;
    const long base = (long)blockIdx.x * 64;
    for (int i = tid; i < 64 * 160; i += 256) {
        int row = i / 160, c = i % 160;
        float v = (c < BOND_FD) ? fb[(base + row) * BOND_FD + c] : 0.f;
        int byte = row * 320 + c * 2;
        *(u16*)(sm + (byte ^ ((row & 7) << 4))) = f2us(v);
    }
    __syncthreads();

    const int lane = tid & 63, wave = tid >> 6;
    const int rbase = wave * 16;
    const int arow = rbase + (lane & 15);
    const int ahi = lane >> 4;
    float4v acc[NT_H];
#pragma unroll
    for (int nt = 0; nt < NT_H; ++nt) acc[nt] = {0.f, 0.f, 0.f, 0.f};
    for (int kk = 0; kk < KK_I; ++kk) {
        int byte = arow * 320 + kk * 64 + ahi * 16;
        short8v a = *(const short8v*)(sm + (byte ^ ((arow & 7) << 4)));
#pragma unroll
        for (int nt = 0; nt < NT_H; ++nt) {
            short8v b = WiP[((kk * NT_H + nt) << 6) + lane];
            acc[nt] = __builtin_amdgcn_mfma_f32_16x16x32_bf16(a, b, acc[nt], 0, 0, 0);
        }
    }
    const int col0 = lane & 15, rg = (lane >> 4) * 4;
#pragma unroll
    for (int nt = 0; nt < NT_H; ++nt) {
        int col = nt * 16 + col0;
        if (col < HIDDEN) {
#pragma unroll
            for (int r = 0; r < 4; ++r) {
                long row_g = base + rbase + rg + r;
                float v = acc[nt][r];
                inp[row_g * HIDDEN + col] = f2us(v);
                msg[row_g * HIDDEN + col] = f2us(fmaxf(v, 0.f));
            }
        }
    }
}

// ---------------------------------------------------------------------------
// K2: amsg[a] = sum_j msg[a2b[a][j]]  — 16 atoms/block, 8B vector gathers.
__global__ __launch_bounds__(256) void k2_gather(const u16* __restrict__ msg,
                                                 const int* __restrict__ a2b,
                                                 u16* __restrict__ amsg) {
    const int tid = threadIdx.x;
    const int t = tid & 15;
    const long a = (long)blockIdx.x * 16 + (tid >> 4);
    int idx[MAX_NB];
#pragma unroll
    for (int j = 0; j < MAX_NB; ++j) idx[j] = a2b[a * MAX_NB + j];
    for (int c = t; c < 75; c += 16) {
        float s0 = 0.f, s1 = 0.f, s2 = 0.f, s3 = 0.f;
#pragma unroll
        for (int j = 0; j < MAX_NB; ++j) {
            uint2 u = ((const uint2*)(msg + (long)idx[j] * HIDDEN))[c];
            s0 += us2f(u.x & 0xffff); s1 += us2f(u.x >> 16);
            s2 += us2f(u.y & 0xffff); s3 += us2f(u.y >> 16);
        }
        uint2 o; o.x = pack2(s0, s1); o.y = pack2(s2, s3);
        ((uint2*)(amsg + a * HIDDEN))[c] = o;
    }
}

// ---------------------------------------------------------------------------
// K3: newmsg = relu(inp + (amsg[b2a] - msg[b2revb]) @ W_h). 64 rows/block.
__global__ __launch_bounds__(256) void k3_update(const u16* __restrict__ inp,
                                                 const u16* __restrict__ msg,
                                                 const u16* __restrict__ amsg,
                                                 const int* __restrict__ b2a,
                                                 const int* __restrict__ b2revb,
                                                 const short8v* __restrict__ WhP,
                                                 u16* __restrict__ outmsg) {
    __shared__ char sm[64 * 640];            // [64 rows][320 bf16], swizzled
    const int tid = threadIdx.x;
    const long base = (long)blockIdx.x * 64;
    for (int i = tid; i < 64 * 80; i += 256) {
        int row = i / 80, c = i % 80;
        long b = base + row;
        uint2 o = {0u, 0u};
        if (c < 75) {
            int ia = b2a[b], ir = b2revb[b];
            uint2 ua = ((const uint2*)(amsg + (long)ia * HIDDEN))[c];
            uint2 ur = ((const uint2*)(msg + (long)ir * HIDDEN))[c];
            o.x = pack2(us2f(ua.x & 0xffff) - us2f(ur.x & 0xffff),
                        us2f(ua.x >> 16)    - us2f(ur.x >> 16));
            o.y = pack2(us2f(ua.y & 0xffff) - us2f(ur.y & 0xffff),
                        us2f(ua.y >> 16)    - us2f(ur.y >> 16));
        }
        int byte = row * 640 + c * 8;
        *(uint2*)(sm + (byte ^ ((row & 7) << 4))) = o;
    }
    __syncthreads();

    const int lane = tid & 63, wave = tid >> 6;
    const int rbase = wave * 16;
    const int arow = rbase + (lane & 15);
    const int ahi = lane >> 4;
    float4v acc[NT_H];
#pragma unroll
    for (int nt = 0; nt < NT_H; ++nt) acc[nt] = {0.f, 0.f, 0.f, 0.f};
    for (int kk = 0; kk < KK_H; ++kk) {
        int byte = arow * 640 + kk * 64 + ahi * 16;
        short8v a = *(const short8v*)(sm + (byte ^ ((arow & 7) << 4)));
#pragma unroll
        for (int nt = 0; nt < NT_H; ++nt) {
            short8v b = WhP[((kk * NT_H + nt) << 6) + lane];
            acc[nt] = __builtin_amdgcn_mfma_f32_16x16x32_bf16(a, b, acc[nt], 0, 0, 0);
        }
    }
    const int col0 = lane & 15, rg = (lane >> 4) * 4;
#pragma unroll
    for (int nt = 0; nt < NT_H; ++nt) {
        int col = nt * 16 + col0;
        if (col < HIDDEN) {
#pragma unroll
            for (int r = 0; r < 4; ++r) {
                long row_g = base + rbase + rg + r;
                float v = us2f(inp[row_g * HIDDEN + col]) + acc[nt][r];
                outmsg[row_g * HIDDEN + col] = f2us(fmaxf(v, 0.f));
            }
        }
    }
}

// ---------------------------------------------------------------------------
// K4: atom_hiddens = relu([amsg | f_atoms](perm) @ WoP + b_o)  -> bf16 ah
__global__ __launch_bounds__(256) void k4_readout(const float* __restrict__ fa,
                                                  const u16* __restrict__ amsg,
                                                  const short8v* __restrict__ WoP,
                                                  const float* __restrict__ bo,
                                                  u16* __restrict__ ah) {
    __shared__ char sm[64 * 896];            // [64 rows][448 bf16], swizzled
    const int tid = threadIdx.x;
    const long base = (long)blockIdx.x * 64;
    // amsg part: cols 0..299
    for (int i = tid; i < 64 * 75; i += 256) {
        int row = i / 75, c = i % 75;
        long a = base + row;
        uint2 o = {0u, 0u};
        if (a < N_ATOMS) o = ((const uint2*)(amsg + a * HIDDEN))[c];
        int byte = row * 896 + c * 8;
        *(uint2*)(sm + (byte ^ ((row & 7) << 4))) = o;
    }
    // f_atoms part: cols 300..432, pad 433..447
    for (int i = tid; i < 64 * 148; i += 256) {
        int row = i / 148, c2 = i % 148;
        long a = base + row;
        float v = (a < N_ATOMS && c2 < ATOM_FD) ? fa[a * ATOM_FD + c2] : 0.f;
        int byte = row * 896 + (HIDDEN + c2) * 2;
        *(u16*)(sm + (byte ^ ((row & 7) << 4))) = f2us(v);
    }
    __syncthreads();

    const int lane = tid & 63, wave = tid >> 6;
    const int rbase = wave * 16;
    const int arow = rbase + (lane & 15);
    const int ahi = lane >> 4;
    float4v acc[NT_H];
#pragma unroll
    for (int nt = 0; nt < NT_H; ++nt) acc[nt] = {0.f, 0.f, 0.f, 0.f};
    for (int kk = 0; kk < KK_O; ++kk) {
        int byte = arow * 896 + kk * 64 + ahi * 16;
        short8v a = *(const short8v*)(sm + (byte ^ ((arow & 7) << 4)));
#pragma unroll
        for (int nt = 0; nt < NT_H; ++nt) {
            short8v b = WoP[((kk * NT_H + nt) << 6) + lane];
            acc[nt] = __builtin_amdgcn_mfma_f32_16x16x32_bf16(a, b, acc[nt], 0, 0, 0);
        }
    }
    const int col0 = lane & 15, rg = (lane >> 4) * 4;
#pragma unroll
    for (int nt = 0; nt < NT_H; ++nt) {
        int col = nt * 16 + col0;
        if (col < HIDDEN) {
            float bias = bo[col];
#pragma unroll
            for (int r = 0; r < 4; ++r) {
                long row_g = base + rbase + rg + r;
                if (row_g < N_ATOMS) {
                    float v = acc[nt][r] + bias;
                    ah[row_g * HIDDEN + col] = f2us(fmaxf(v, 0.f));
                }
            }
        }
    }
}

// ---------------------------------------------------------------------------
// K5: mean-pool 20 contiguous atoms per molecule.
__global__ __launch_bounds__(320) void k5_pool(const u16* __restrict__ ah,
                                               float* __restrict__ out) {
    const int h = threadIdx.x;
    const int mol = blockIdx.x;
    if (h >= HIDDEN) return;
    float s = 0.f;
#pragma unroll
    for (int a = 0; a < APM; ++a)
        s += us2f(ah[((long)mol * APM + a) * HIDDEN + h]);
    out[(long)mol * HIDDEN + h] = s * (1.f / APM);
}

// ---------------------------------------------------------------------------
extern "C" void kernel_launch(void* const* d_in, const int* in_sizes, int n_in,
                              void* d_out, int out_size, void* d_ws, size_t ws_size,
                              hipStream_t stream) {
    const float* f_atoms = (const float*)d_in[0];
    const float* f_bonds = (const float*)d_in[1];
    const int* a2b = (const int*)d_in[2];
    const int* b2a = (const int*)d_in[3];
    const int* b2revb = (const int*)d_in[4];
    const float* Wi = (const float*)d_in[6];
    const float* Wh = (const float*)d_in[7];
    const float* Wo = (const float*)d_in[8];
    const float* bo = (const float*)d_in[9];
    float* out = (float*)d_out;

    char* ws = (char*)d_ws;
    size_t off = 0;
    auto alloc = [&](size_t bytes) {
        void* p = ws + off;
        off = (off + bytes + 255) & ~(size_t)255;
        return p;
    };
    u16* inp  = (u16*)alloc((size_t)N_BONDS * HIDDEN * sizeof(u16));
    u16* msgA = (u16*)alloc((size_t)N_BONDS * HIDDEN * sizeof(u16));
    u16* msgB = (u16*)alloc((size_t)N_BONDS * HIDDEN * sizeof(u16));
    u16* amsg = (u16*)alloc((size_t)N_ATOMS * HIDDEN * sizeof(u16));
    short* WiP = (short*)alloc((size_t)KK_I * NT_H * 64 * 8 * sizeof(short));
    short* WhP = (short*)alloc((size_t)KK_H * NT_H * 64 * 8 * sizeof(short));
    short* WoP = (short*)alloc((size_t)KK_O * NT_H * 64 * 8 * sizeof(short));
    u16* ah = inp;   // reuse: inp is dead after the 2nd k3

    // pack weights into MFMA fragment order (bf16)
    pack_w<<<KK_I * NT_H, 64, 0, stream>>>(Wi, WiP, BOND_FD, 0);
    pack_w<<<KK_H * NT_H, 64, 0, stream>>>(Wh, WhP, HIDDEN, 0);
    pack_w<<<KK_O * NT_H, 64, 0, stream>>>(Wo, WoP, ATOM_FD + HIDDEN, 2);

    k1_input<<<N_BONDS / 64, 256, 0, stream>>>(f_bonds, (const short8v*)WiP, inp, msgA);

    k2_gather<<<N_ATOMS / 16, 256, 0, stream>>>(msgA, a2b, amsg);
    k3_update<<<N_BONDS / 64, 256, 0, stream>>>(inp, msgA, amsg, b2a, b2revb,
                                                (const short8v*)WhP, msgB);

    k2_gather<<<N_ATOMS / 16, 256, 0, stream>>>(msgB, a2b, amsg);
    k3_update<<<N_BONDS / 64, 256, 0, stream>>>(inp, msgB, amsg, b2a, b2revb,
                                                (const short8v*)WhP, msgA);

    k2_gather<<<N_ATOMS / 16, 256, 0, stream>>>(msgA, a2b, amsg);
    k4_readout<<<(N_ATOMS + 63) / 64, 256, 0, stream>>>(f_atoms, amsg,
                                                        (const short8v*)WoP, bo, ah);
    k5_pool<<<N_MOLS, 320, 0, stream>>>(ah, out);
}

// Round 3
// 1050.382 us; speedup vs baseline: 3.2991x; 1.7146x over previous
//
#include <hip/hip_runtime.h>
#include <hip/hip_bf16.h>

#define N_ATOMS 100000
#define N_BONDS 200000
#define MAX_NB 6
#define HIDDEN 300
#define HP 320               // padded hidden: row = 640 B = 40 x 16B chunks
#define CH 40
#define ATOM_FD 133
#define BOND_FD 147
#define N_MOLS 5000
#define APM 20

#define NT 20                // 20*16 = 320 output cols (300 real + 20 zeros)
#define NTO 19               // k4 readout col tiles (304 >= 300)
#define KK_I 5               // K=160 >= 147
#define KK_H 10              // K=320 >= 300
#define KK_O 14              // K=448 >= 433

using bf16 = __hip_bfloat16;
typedef __attribute__((ext_vector_type(8))) short short8v;
typedef __attribute__((ext_vector_type(4))) float float4v;
typedef unsigned int u32;
typedef unsigned short u16;

__device__ __forceinline__ float us2f(u16 u) {
    union { u32 i; float f; } v; v.i = ((u32)u) << 16; return v.f;
}
__device__ __forceinline__ u16 f2us(float f) {
    bf16 h = __float2bfloat16(f);
    return *(u16*)&h;
}
__device__ __forceinline__ u32 pack2(float a, float b) {
    return (u32)f2us(a) | ((u32)f2us(b) << 16);
}

// ---------------------------------------------------------------------------
// pack_w: W [Ksrc x 300] fp32 -> bf16 MFMA-B fragments [KK][NTX][64][8]
// mode==2 (W_o): K layout is [amsg(0..299) | f_atoms(300..432)].
__global__ __launch_bounds__(64) void pack_w(const float* __restrict__ src,
                                             short* __restrict__ dst,
                                             int Ksrc, int NTX, int mode) {
    int kk = blockIdx.x / NTX, nt = blockIdx.x % NTX;
    int lane = threadIdx.x;
    int col = nt * 16 + (lane & 15);
#pragma unroll
    for (int j = 0; j < 8; ++j) {
        int k = kk * 32 + (lane >> 4) * 8 + j;
        float v = 0.f;
        if (k < Ksrc && col < HIDDEN) {
            int krow = k;
            if (mode == 2) krow = (k < HIDDEN) ? (ATOM_FD + k) : (k - HIDDEN);
            v = src[krow * HIDDEN + col];
        }
        dst[(((kk * NTX + nt) << 6) + lane) * 8 + j] = (short)f2us(v);
    }
}

// ---------------------------------------------------------------------------
// K1: inp = f_bonds @ W_i ; msg = relu(inp). 64 rows/block, wave-nt split.
// Outputs padded stride HP with exact-zero pad columns.
__global__ __launch_bounds__(256) void k1_input(const float* __restrict__ fb,
                                                const short8v* __restrict__ WiP,
                                                u16* __restrict__ inp,
                                                u16* __restrict__ msg) {
    __shared__ char sm[64 * 320];            // [64 rows][160 bf16], swizzled
    const int tid = threadIdx.x;
    const long base = (long)blockIdx.x * 64;
    for (int i = tid; i < 64 * 160; i += 256) {
        int row = i / 160, c = i % 160;
        float v = (c < BOND_FD) ? fb[(base + row) * BOND_FD + c] : 0.f;
        int byte = row * 320 + c * 2;
        *(u16*)(sm + (byte ^ ((row & 7) << 4))) = f2us(v);
    }
    __syncthreads();

    const int lane = tid & 63, wave = tid >> 6;
    const int nt0 = wave * 5;
    const int arow0 = lane & 15, ahi = lane >> 4;
    float4v acc[5][4];
#pragma unroll
    for (int nt = 0; nt < 5; ++nt)
#pragma unroll
        for (int rg = 0; rg < 4; ++rg) acc[nt][rg] = {0.f, 0.f, 0.f, 0.f};
    for (int kk = 0; kk < KK_I; ++kk) {
        short8v a[4];
#pragma unroll
        for (int rg = 0; rg < 4; ++rg) {
            int row = rg * 16 + arow0;
            int byte = row * 320 + kk * 64 + ahi * 16;
            a[rg] = *(const short8v*)(sm + (byte ^ ((row & 7) << 4)));
        }
#pragma unroll
        for (int nt = 0; nt < 5; ++nt) {
            short8v b = WiP[((kk * NT + nt0 + nt) << 6) + lane];
#pragma unroll
            for (int rg = 0; rg < 4; ++rg)
                acc[nt][rg] = __builtin_amdgcn_mfma_f32_16x16x32_bf16(a[rg], b, acc[nt][rg], 0, 0, 0);
        }
    }
    const int col0 = lane & 15, rq = (lane >> 4) * 4;
#pragma unroll
    for (int nt = 0; nt < 5; ++nt) {
        int col = (nt0 + nt) * 16 + col0;   // pad cols get acc==0 (zero B-pack)
#pragma unroll
        for (int rg = 0; rg < 4; ++rg)
#pragma unroll
            for (int r = 0; r < 4; ++r) {
                long row_g = base + rg * 16 + rq + r;
                float v = acc[nt][rg][r];
                inp[row_g * HP + col] = f2us(v);
                msg[row_g * HP + col] = f2us(fmaxf(v, 0.f));
            }
    }
}

// ---------------------------------------------------------------------------
// KZ: Z = A @ W_h — dense contiguous GEMM, 64 rows/block, wave-nt split.
__global__ __launch_bounds__(256) void kz_gemm(const u16* __restrict__ A,
                                               const short8v* __restrict__ BP,
                                               u16* __restrict__ Zout) {
    __shared__ char sm[64 * 640];            // [64 rows][320 bf16], swizzled
    const int tid = threadIdx.x;
    const long base = (long)blockIdx.x * 64;
#pragma unroll
    for (int it = 0; it < 10; ++it) {
        int i = tid + it * 256;
        int row = i / CH, c = i % CH;
        uint4 v = ((const uint4*)(A + (base + row) * HP))[c];
        int byte = row * 640 + c * 16;
        *(uint4*)(sm + (byte ^ ((row & 7) << 4))) = v;
    }
    __syncthreads();

    const int lane = tid & 63, wave = tid >> 6;
    const int nt0 = wave * 5;
    const int arow0 = lane & 15, ahi = lane >> 4;
    float4v acc[5][4];
#pragma unroll
    for (int nt = 0; nt < 5; ++nt)
#pragma unroll
        for (int rg = 0; rg < 4; ++rg) acc[nt][rg] = {0.f, 0.f, 0.f, 0.f};
    for (int kk = 0; kk < KK_H; ++kk) {
        short8v a[4];
#pragma unroll
        for (int rg = 0; rg < 4; ++rg) {
            int row = rg * 16 + arow0;
            int byte = row * 640 + kk * 64 + ahi * 16;
            a[rg] = *(const short8v*)(sm + (byte ^ ((row & 7) << 4)));
        }
#pragma unroll
        for (int nt = 0; nt < 5; ++nt) {
            short8v b = BP[((kk * NT + nt0 + nt) << 6) + lane];
#pragma unroll
            for (int rg = 0; rg < 4; ++rg)
                acc[nt][rg] = __builtin_amdgcn_mfma_f32_16x16x32_bf16(a[rg], b, acc[nt][rg], 0, 0, 0);
        }
    }
    const int col0 = lane & 15, rq = (lane >> 4) * 4;
#pragma unroll
    for (int nt = 0; nt < 5; ++nt) {
        int col = (nt0 + nt) * 16 + col0;
#pragma unroll
        for (int rg = 0; rg < 4; ++rg)
#pragma unroll
            for (int r = 0; r < 4; ++r)
                Zout[(base + rg * 16 + rq + r) * HP + col] = f2us(acc[nt][rg][r]);
    }
}

// ---------------------------------------------------------------------------
// K2G: dst[a] = sum_j src[a2b[a][j]] — flat thread-per-16B-chunk, no LDS.
__global__ __launch_bounds__(256) void k2_gather(const u16* __restrict__ src,
                                                 const int* __restrict__ a2b,
                                                 u16* __restrict__ dst) {
    int id = blockIdx.x * 256 + threadIdx.x;       // < 4M
    int atom = id / CH, c = id % CH;
    const int* nb = a2b + atom * MAX_NB;
    float s0=0,s1=0,s2=0,s3=0,s4=0,s5=0,s6=0,s7=0;
#pragma unroll
    for (int j = 0; j < MAX_NB; ++j) {
        int b = nb[j];
        uint4 u = ((const uint4*)(src + (long)b * HP))[c];
        s0 += us2f(u.x & 0xffff); s1 += us2f(u.x >> 16);
        s2 += us2f(u.y & 0xffff); s3 += us2f(u.y >> 16);
        s4 += us2f(u.z & 0xffff); s5 += us2f(u.z >> 16);
        s6 += us2f(u.w & 0xffff); s7 += us2f(u.w >> 16);
    }
    uint4 o;
    o.x = pack2(s0, s1); o.y = pack2(s2, s3);
    o.z = pack2(s4, s5); o.w = pack2(s6, s7);
    ((uint4*)(dst + (long)atom * HP))[c] = o;
}

// ---------------------------------------------------------------------------
// KE: msg = relu(inp + ZA[b2a] - Z[b2revb]) — flat elementwise, no LDS.
__global__ __launch_bounds__(256) void ke_update(const u16* __restrict__ inp,
                                                 const u16* __restrict__ ZA,
                                                 const u16* __restrict__ Z,
                                                 const int* __restrict__ b2a,
                                                 const int* __restrict__ b2revb,
                                                 u16* __restrict__ msg) {
    int id = blockIdx.x * 256 + threadIdx.x;       // < 8M
    int bond = id / CH, c = id % CH;
    int ia = b2a[bond], ir = b2revb[bond];
    uint4 ua = ((const uint4*)(ZA + (long)ia * HP))[c];
    uint4 uz = ((const uint4*)(Z + (long)ir * HP))[c];
    uint4 un = ((const uint4*)(inp + (long)bond * HP))[c];
    uint4 o;
#define EL(w) { \
        float lo = us2f(un.w & 0xffff) + us2f(ua.w & 0xffff) - us2f(uz.w & 0xffff); \
        float hi = us2f(un.w >> 16)    + us2f(ua.w >> 16)    - us2f(uz.w >> 16);    \
        o.w = pack2(fmaxf(lo, 0.f), fmaxf(hi, 0.f)); }
    EL(x) EL(y) EL(z) EL(w)
#undef EL
    ((uint4*)(msg + (long)bond * HP))[c] = o;
}

// ---------------------------------------------------------------------------
// K4: ah = relu([amsg | f_atoms] @ WoP + b_o) — wave-nt split, padded amsg in.
__global__ __launch_bounds__(256) void k4_readout(const float* __restrict__ fa,
                                                  const u16* __restrict__ amsg,
                                                  const short8v* __restrict__ WoP,
                                                  const float* __restrict__ bo,
                                                  u16* __restrict__ ah) {
    __shared__ char sm[64 * 896];            // [64 rows][448 bf16], swizzled
    const int tid = threadIdx.x;
    const long base = (long)blockIdx.x * 64;
    for (int i = tid; i < 64 * 75; i += 256) {   // amsg cols 0..299
        int row = i / 75, c = i % 75;
        long a = base + row;
        uint2 o = {0u, 0u};
        if (a < N_ATOMS) o = ((const uint2*)(amsg + a * HP))[c];
        int byte = row * 896 + c * 8;
        *(uint2*)(sm + (byte ^ ((row & 7) << 4))) = o;
    }
    for (int i = tid; i < 64 * 148; i += 256) {  // f_atoms cols 300..432 + pad
        int row = i / 148, c2 = i % 148;
        long a = base + row;
        float v = (a < N_ATOMS && c2 < ATOM_FD) ? fa[a * ATOM_FD + c2] : 0.f;
        int byte = row * 896 + (HIDDEN + c2) * 2;
        *(u16*)(sm + (byte ^ ((row & 7) << 4))) = f2us(v);
    }
    __syncthreads();

    const int lane = tid & 63, wave = tid >> 6;
    const int nt0 = wave * 5;                    // waves cover 5/5/5/4 of 19
    const int arow0 = lane & 15, ahi = lane >> 4;
    float4v acc[5][4];
#pragma unroll
    for (int nt = 0; nt < 5; ++nt)
#pragma unroll
        for (int rg = 0; rg < 4; ++rg) acc[nt][rg] = {0.f, 0.f, 0.f, 0.f};
    for (int kk = 0; kk < KK_O; ++kk) {
        short8v a[4];
#pragma unroll
        for (int rg = 0; rg < 4; ++rg) {
            int row = rg * 16 + arow0;
            int byte = row * 896 + kk * 64 + ahi * 16;
            a[rg] = *(const short8v*)(sm + (byte ^ ((row & 7) << 4)));
        }
#pragma unroll
        for (int nt = 0; nt < 5; ++nt) {
            if (nt0 + nt < NTO) {
                short8v b = WoP[((kk * NTO + nt0 + nt) << 6) + lane];
#pragma unroll
                for (int rg = 0; rg < 4; ++rg)
                    acc[nt][rg] = __builtin_amdgcn_mfma_f32_16x16x32_bf16(a[rg], b, acc[nt][rg], 0, 0, 0);
            }
        }
    }
    const int col0 = lane & 15, rq = (lane >> 4) * 4;
#pragma unroll
    for (int nt = 0; nt < 5; ++nt) {
        int col = (nt0 + nt) * 16 + col0;
        if (col < HIDDEN) {
            float bias = bo[col];
#pragma unroll
            for (int rg = 0; rg < 4; ++rg)
#pragma unroll
                for (int r = 0; r < 4; ++r) {
                    long row_g = base + rg * 16 + rq + r;
                    if (row_g < N_ATOMS)
                        ah[row_g * HIDDEN + col] = f2us(fmaxf(acc[nt][rg][r] + bias, 0.f));
                }
        }
    }
}

// ---------------------------------------------------------------------------
// K5: mean-pool 20 contiguous atoms per molecule.
__global__ __launch_bounds__(320) void k5_pool(const u16* __restrict__ ah,
                                               float* __restrict__ out) {
    const int h = threadIdx.x;
    const int mol = blockIdx.x;
    if (h >= HIDDEN) return;
    float s = 0.f;
#pragma unroll
    for (int a = 0; a < APM; ++a)
        s += us2f(ah[((long)mol * APM + a) * HIDDEN + h]);
    out[(long)mol * HIDDEN + h] = s * (1.f / APM);
}

// ---------------------------------------------------------------------------
extern "C" void kernel_launch(void* const* d_in, const int* in_sizes, int n_in,
                              void* d_out, int out_size, void* d_ws, size_t ws_size,
                              hipStream_t stream) {
    const float* f_atoms = (const float*)d_in[0];
    const float* f_bonds = (const float*)d_in[1];
    const int* a2b = (const int*)d_in[2];
    const int* b2a = (const int*)d_in[3];
    const int* b2revb = (const int*)d_in[4];
    const float* Wi = (const float*)d_in[6];
    const float* Wh = (const float*)d_in[7];
    const float* Wo = (const float*)d_in[8];
    const float* bo = (const float*)d_in[9];
    float* out = (float*)d_out;

    char* ws = (char*)d_ws;
    size_t off = 0;
    auto alloc = [&](size_t bytes) {
        void* p = ws + off;
        off = (off + bytes + 255) & ~(size_t)255;
        return p;
    };
    u16* inp = (u16*)alloc((size_t)N_BONDS * HP * sizeof(u16));   // 128 MB
    u16* msg = (u16*)alloc((size_t)N_BONDS * HP * sizeof(u16));   // 128 MB
    u16* Z   = (u16*)alloc((size_t)N_BONDS * HP * sizeof(u16));   // 128 MB
    u16* ZA  = (u16*)alloc((size_t)N_ATOMS * HP * sizeof(u16));   //  64 MB
    short* WiP = (short*)alloc((size_t)KK_I * NT * 64 * 8 * sizeof(short));
    short* WhP = (short*)alloc((size_t)KK_H * NT * 64 * 8 * sizeof(short));
    short* WoP = (short*)alloc((size_t)KK_O * NTO * 64 * 8 * sizeof(short));
    u16* ah = Z;   // Z is dead before k4

    pack_w<<<KK_I * NT, 64, 0, stream>>>(Wi, WiP, BOND_FD, NT, 0);
    pack_w<<<KK_H * NT, 64, 0, stream>>>(Wh, WhP, HIDDEN, NT, 0);
    pack_w<<<KK_O * NTO, 64, 0, stream>>>(Wo, WoP, ATOM_FD + HIDDEN, NTO, 2);

    k1_input<<<N_BONDS / 64, 256, 0, stream>>>(f_bonds, (const short8v*)WiP, inp, msg);

    for (int it = 0; it < 2; ++it) {
        kz_gemm<<<N_BONDS / 64, 256, 0, stream>>>(msg, (const short8v*)WhP, Z);
        k2_gather<<<N_ATOMS * CH / 256, 256, 0, stream>>>(Z, a2b, ZA);
        ke_update<<<N_BONDS * CH / 256, 256, 0, stream>>>(inp, ZA, Z, b2a, b2revb, msg);
    }

    k2_gather<<<N_ATOMS * CH / 256, 256, 0, stream>>>(msg, a2b, ZA);
    k4_readout<<<(N_ATOMS + 63) / 64, 256, 0, stream>>>(f_atoms, ZA,
                                                        (const short8v*)WoP, bo, ah);
    k5_pool<<<N_MOLS, 320, 0, stream>>>(ah, out);
}

// Round 4
// 931.160 us; speedup vs baseline: 3.7216x; 1.1280x over previous
//
#include <hip/hip_runtime.h>
#include <hip/hip_bf16.h>

#define N_ATOMS 100000
#define N_BONDS 200000
#define MAX_NB 6
#define HIDDEN 300
#define HP 320               // padded hidden: row = 640 B = 40 x 16B chunks
#define CH 40
#define ATOM_FD 133
#define BOND_FD 147
#define N_MOLS 5000
#define APM 20

#define NT 20                // 20*16 = 320 output cols (300 real + 20 zero)
#define KK_I 5               // K=160 >= 147
#define KK_H 10              // K=320 >= 300
#define KK_O 14              // K=448 >= 433

using bf16 = __hip_bfloat16;
typedef __attribute__((ext_vector_type(8))) short short8v;
typedef __attribute__((ext_vector_type(4))) float float4v;
typedef unsigned int u32;
typedef unsigned short u16;

__device__ __forceinline__ float us2f(u16 u) {
    union { u32 i; float f; } v; v.i = ((u32)u) << 16; return v.f;
}
__device__ __forceinline__ u16 f2us(float f) {
    bf16 h = __float2bfloat16(f);
    return *(u16*)&h;
}
__device__ __forceinline__ u32 pack2(float a, float b) {
    return (u32)f2us(a) | ((u32)f2us(b) << 16);
}
__device__ __forceinline__ uint2 pack4(const float4v& a) {
    uint2 o; o.x = pack2(a[0], a[1]); o.y = pack2(a[2], a[3]); return o;
}
// relu on 2 packed bf16
__device__ __forceinline__ u32 relu2(u32 u) {
    u32 r = (u & 0x80000000u) ? (u & 0x0000ffffu) : u;
    r = (r & 0x8000u) ? (r & 0xffff0000u) : r;
    return r;
}
__device__ __forceinline__ uint4 relu8(uint4 u) {
    u.x = relu2(u.x); u.y = relu2(u.y); u.z = relu2(u.z); u.w = relu2(u.w);
    return u;
}

// ---------------------------------------------------------------------------
// pack_w: W [Ksrc x 300] fp32 -> bf16 MFMA-B fragments [KK][NTX][64][8]
// mode==2 (W_o): K layout is [amsg(0..299) | f_atoms(300..432)].
__global__ __launch_bounds__(64) void pack_w(const float* __restrict__ src,
                                             short* __restrict__ dst,
                                             int Ksrc, int NTX, int mode) {
    int kk = blockIdx.x / NTX, nt = blockIdx.x % NTX;
    int lane = threadIdx.x;
    int col = nt * 16 + (lane & 15);
#pragma unroll
    for (int j = 0; j < 8; ++j) {
        int k = kk * 32 + (lane >> 4) * 8 + j;
        float v = 0.f;
        if (k < Ksrc && col < HIDDEN) {
            int krow = k;
            if (mode == 2) krow = (k < HIDDEN) ? (ATOM_FD + k) : (k - HIDDEN);
            v = src[krow * HIDDEN + col];
        }
        dst[(((kk * NTX + nt) << 6) + lane) * 8 + j] = (short)f2us(v);
    }
}

// ---------------------------------------------------------------------------
// K1: inp = f_bonds @ W_i. 64 rows/block, wave-nt split, swapped-operand MFMA,
// LDS-assembled uint4 epilogue. (msg is NOT materialized; kz<1> relus inp.)
__global__ __launch_bounds__(256) void k1_input(const float* __restrict__ fb,
                                                const short8v* __restrict__ WiP,
                                                u16* __restrict__ inp) {
    __shared__ char sm[64 * 640];            // stage uses 20KB region layout
    const int tid = threadIdx.x;
    const long base = (long)blockIdx.x * 64;
    for (int i = tid; i < 64 * 160; i += 256) {
        int row = i / 160, c = i % 160;
        float v = (c < BOND_FD) ? fb[(base + row) * BOND_FD + c] : 0.f;
        int byte = row * 320 + c * 2;
        *(u16*)(sm + (byte ^ ((row & 7) << 4))) = f2us(v);
    }
    __syncthreads();

    const int lane = tid & 63, wave = tid >> 6;
    const int nt0 = wave * 5;
    const int arow0 = lane & 15, ahi = lane >> 4;
    float4v acc[5][4];
#pragma unroll
    for (int nt = 0; nt < 5; ++nt)
#pragma unroll
        for (int rg = 0; rg < 4; ++rg) acc[nt][rg] = {0.f, 0.f, 0.f, 0.f};
    for (int kk = 0; kk < KK_I; ++kk) {
        short8v a[4];
#pragma unroll
        for (int rg = 0; rg < 4; ++rg) {
            int row = rg * 16 + arow0;
            int byte = row * 320 + kk * 64 + ahi * 16;
            a[rg] = *(const short8v*)(sm + (byte ^ ((row & 7) << 4)));
        }
#pragma unroll
        for (int nt = 0; nt < 5; ++nt) {
            short8v b = WiP[((kk * NT + nt0 + nt) << 6) + lane];
#pragma unroll
            for (int rg = 0; rg < 4; ++rg)   // swapped: acc = B^T A^T = C^T
                acc[nt][rg] = __builtin_amdgcn_mfma_f32_16x16x32_bf16(b, a[rg], acc[nt][rg], 0, 0, 0);
        }
    }
    __syncthreads();
    // lane holds C[row = l&15 (+rg*16)][col = (nt0+nt)*16 + (l>>4)*4 + q]
#pragma unroll
    for (int nt = 0; nt < 5; ++nt)
#pragma unroll
        for (int rg = 0; rg < 4; ++rg) {
            int row = rg * 16 + arow0;
            int byte = row * 640 + (nt0 + nt) * 32 + ahi * 8;
            *(uint2*)(sm + (byte ^ ((row & 7) << 4))) = pack4(acc[nt][rg]);
        }
    __syncthreads();
#pragma unroll
    for (int it = 0; it < 10; ++it) {
        int id = tid + it * 256;
        int row = id / CH, c = id % CH;
        int byte = row * 640 + c * 16;
        uint4 v = *(const uint4*)(sm + (byte ^ ((row & 7) << 4)));
        ((uint4*)(inp + (base + row) * HP))[c] = v;
    }
}

// ---------------------------------------------------------------------------
// KZ: Z = act(A) @ W_h — dense GEMM; RELU applies relu while staging.
template<int RELU>
__global__ __launch_bounds__(256) void kz_gemm(const u16* __restrict__ A,
                                               const short8v* __restrict__ BP,
                                               u16* __restrict__ Zout) {
    __shared__ char sm[64 * 640];
    const int tid = threadIdx.x;
    const long base = (long)blockIdx.x * 64;
#pragma unroll
    for (int it = 0; it < 10; ++it) {
        int i = tid + it * 256;
        int row = i / CH, c = i % CH;
        uint4 v = ((const uint4*)(A + (base + row) * HP))[c];
        if (RELU) v = relu8(v);
        int byte = row * 640 + c * 16;
        *(uint4*)(sm + (byte ^ ((row & 7) << 4))) = v;
    }
    __syncthreads();

    const int lane = tid & 63, wave = tid >> 6;
    const int nt0 = wave * 5;
    const int arow0 = lane & 15, ahi = lane >> 4;
    float4v acc[5][4];
#pragma unroll
    for (int nt = 0; nt < 5; ++nt)
#pragma unroll
        for (int rg = 0; rg < 4; ++rg) acc[nt][rg] = {0.f, 0.f, 0.f, 0.f};
    for (int kk = 0; kk < KK_H; ++kk) {
        short8v a[4];
#pragma unroll
        for (int rg = 0; rg < 4; ++rg) {
            int row = rg * 16 + arow0;
            int byte = row * 640 + kk * 64 + ahi * 16;
            a[rg] = *(const short8v*)(sm + (byte ^ ((row & 7) << 4)));
        }
#pragma unroll
        for (int nt = 0; nt < 5; ++nt) {
            short8v b = BP[((kk * NT + nt0 + nt) << 6) + lane];
#pragma unroll
            for (int rg = 0; rg < 4; ++rg)
                acc[nt][rg] = __builtin_amdgcn_mfma_f32_16x16x32_bf16(b, a[rg], acc[nt][rg], 0, 0, 0);
        }
    }
    __syncthreads();
#pragma unroll
    for (int nt = 0; nt < 5; ++nt)
#pragma unroll
        for (int rg = 0; rg < 4; ++rg) {
            int row = rg * 16 + arow0;
            int byte = row * 640 + (nt0 + nt) * 32 + ahi * 8;
            *(uint2*)(sm + (byte ^ ((row & 7) << 4))) = pack4(acc[nt][rg]);
        }
    __syncthreads();
#pragma unroll
    for (int it = 0; it < 10; ++it) {
        int id = tid + it * 256;
        int row = id / CH, c = id % CH;
        int byte = row * 640 + c * 16;
        uint4 v = *(const uint4*)(sm + (byte ^ ((row & 7) << 4)));
        ((uint4*)(Zout + (base + row) * HP))[c] = v;
    }
}

// ---------------------------------------------------------------------------
// K2G: dst[a] = sum_j src[a2b[a][j]] — flat thread-per-16B-chunk, no LDS.
__global__ __launch_bounds__(256) void k2_gather(const u16* __restrict__ src,
                                                 const int* __restrict__ a2b,
                                                 u16* __restrict__ dst) {
    int id = blockIdx.x * 256 + threadIdx.x;
    int atom = id / CH, c = id % CH;
    const int* nb = a2b + atom * MAX_NB;
    float s0=0,s1=0,s2=0,s3=0,s4=0,s5=0,s6=0,s7=0;
#pragma unroll
    for (int j = 0; j < MAX_NB; ++j) {
        int b = nb[j];
        uint4 u = ((const uint4*)(src + (long)b * HP))[c];
        s0 += us2f(u.x & 0xffff); s1 += us2f(u.x >> 16);
        s2 += us2f(u.y & 0xffff); s3 += us2f(u.y >> 16);
        s4 += us2f(u.z & 0xffff); s5 += us2f(u.z >> 16);
        s6 += us2f(u.w & 0xffff); s7 += us2f(u.w >> 16);
    }
    uint4 o;
    o.x = pack2(s0, s1); o.y = pack2(s2, s3);
    o.z = pack2(s4, s5); o.w = pack2(s6, s7);
    ((uint4*)(dst + (long)atom * HP))[c] = o;
}

// ---------------------------------------------------------------------------
// KE: msg = relu(inp + ZA[b2a] - Z[b2revb]) — flat elementwise, no LDS.
__global__ __launch_bounds__(256) void ke_update(const u16* __restrict__ inp,
                                                 const u16* __restrict__ ZA,
                                                 const u16* __restrict__ Z,
                                                 const int* __restrict__ b2a,
                                                 const int* __restrict__ b2revb,
                                                 u16* __restrict__ msg) {
    int id = blockIdx.x * 256 + threadIdx.x;
    int bond = id / CH, c = id % CH;
    int ia = b2a[bond], ir = b2revb[bond];
    uint4 ua = ((const uint4*)(ZA + (long)ia * HP))[c];
    uint4 uz = ((const uint4*)(Z + (long)ir * HP))[c];
    uint4 un = ((const uint4*)(inp + (long)bond * HP))[c];
    uint4 o;
#define EL(w) { \
        float lo = us2f(un.w & 0xffff) + us2f(ua.w & 0xffff) - us2f(uz.w & 0xffff); \
        float hi = us2f(un.w >> 16)    + us2f(ua.w >> 16)    - us2f(uz.w >> 16);    \
        o.w = pack2(fmaxf(lo, 0.f), fmaxf(hi, 0.f)); }
    EL(x) EL(y) EL(z) EL(w)
#undef EL
    ((uint4*)(msg + (long)bond * HP))[c] = o;
}

// ---------------------------------------------------------------------------
// K4: ah = relu([amsg | f_atoms] @ WoP + b_o) — swapped MFMA + LDS epilogue.
__global__ __launch_bounds__(256) void k4_readout(const float* __restrict__ fa,
                                                  const u16* __restrict__ amsg,
                                                  const short8v* __restrict__ WoP,
                                                  const float* __restrict__ bo,
                                                  u16* __restrict__ ah) {
    __shared__ char sm[64 * 896];            // stage 56KB; epilogue reuses 40KB
    const int tid = threadIdx.x;
    const long base = (long)blockIdx.x * 64;
    for (int i = tid; i < 64 * 75; i += 256) {   // amsg cols 0..299
        int row = i / 75, c = i % 75;
        long a = base + row;
        uint2 o = {0u, 0u};
        if (a < N_ATOMS) o = ((const uint2*)(amsg + a * HP))[c];
        int byte = row * 896 + c * 8;
        *(uint2*)(sm + (byte ^ ((row & 7) << 4))) = o;
    }
    for (int i = tid; i < 64 * 148; i += 256) {  // f_atoms cols 300..432 + pad
        int row = i / 148, c2 = i % 148;
        long a = base + row;
        float v = (a < N_ATOMS && c2 < ATOM_FD) ? fa[a * ATOM_FD + c2] : 0.f;
        int byte = row * 896 + (HIDDEN + c2) * 2;
        *(u16*)(sm + (byte ^ ((row & 7) << 4))) = f2us(v);
    }
    __syncthreads();

    const int lane = tid & 63, wave = tid >> 6;
    const int nt0 = wave * 5;
    const int arow0 = lane & 15, ahi = lane >> 4;
    float4v acc[5][4];
#pragma unroll
    for (int nt = 0; nt < 5; ++nt)
#pragma unroll
        for (int rg = 0; rg < 4; ++rg) acc[nt][rg] = {0.f, 0.f, 0.f, 0.f};
    for (int kk = 0; kk < KK_O; ++kk) {
        short8v a[4];
#pragma unroll
        for (int rg = 0; rg < 4; ++rg) {
            int row = rg * 16 + arow0;
            int byte = row * 896 + kk * 64 + ahi * 16;
            a[rg] = *(const short8v*)(sm + (byte ^ ((row & 7) << 4)));
        }
#pragma unroll
        for (int nt = 0; nt < 5; ++nt) {
            short8v b = WoP[((kk * NT + nt0 + nt) << 6) + lane];
#pragma unroll
            for (int rg = 0; rg < 4; ++rg)
                acc[nt][rg] = __builtin_amdgcn_mfma_f32_16x16x32_bf16(b, a[rg], acc[nt][rg], 0, 0, 0);
        }
    }
    __syncthreads();
#pragma unroll
    for (int nt = 0; nt < 5; ++nt) {
        int colb = (nt0 + nt) * 16 + ahi * 4;
        float bias[4];
#pragma unroll
        for (int q = 0; q < 4; ++q)
            bias[q] = (colb + q < HIDDEN) ? bo[colb + q] : 0.f;
#pragma unroll
        for (int rg = 0; rg < 4; ++rg) {
            int row = rg * 16 + arow0;
            float4v v;
#pragma unroll
            for (int q = 0; q < 4; ++q) v[q] = fmaxf(acc[nt][rg][q] + bias[q], 0.f);
            int byte = row * 640 + (nt0 + nt) * 32 + ahi * 8;
            *(uint2*)(sm + (byte ^ ((row & 7) << 4))) = pack4(v);
        }
    }
    __syncthreads();
#pragma unroll
    for (int it = 0; it < 10; ++it) {
        int id = tid + it * 256;
        int row = id / CH, c = id % CH;
        long row_g = base + row;
        if (row_g < N_ATOMS) {
            int byte = row * 640 + c * 16;
            uint4 v = *(const uint4*)(sm + (byte ^ ((row & 7) << 4)));
            ((uint4*)(ah + row_g * HP))[c] = v;
        }
    }
}

// ---------------------------------------------------------------------------
// K5: mean-pool 20 contiguous atoms per molecule.
__global__ __launch_bounds__(320) void k5_pool(const u16* __restrict__ ah,
                                               float* __restrict__ out) {
    const int h = threadIdx.x;
    const int mol = blockIdx.x;
    if (h >= HIDDEN) return;
    float s = 0.f;
#pragma unroll
    for (int a = 0; a < APM; ++a)
        s += us2f(ah[((long)mol * APM + a) * HP + h]);
    out[(long)mol * HIDDEN + h] = s * (1.f / APM);
}

// ---------------------------------------------------------------------------
extern "C" void kernel_launch(void* const* d_in, const int* in_sizes, int n_in,
                              void* d_out, int out_size, void* d_ws, size_t ws_size,
                              hipStream_t stream) {
    const float* f_atoms = (const float*)d_in[0];
    const float* f_bonds = (const float*)d_in[1];
    const int* a2b = (const int*)d_in[2];
    const int* b2a = (const int*)d_in[3];
    const int* b2revb = (const int*)d_in[4];
    const float* Wi = (const float*)d_in[6];
    const float* Wh = (const float*)d_in[7];
    const float* Wo = (const float*)d_in[8];
    const float* bo = (const float*)d_in[9];
    float* out = (float*)d_out;

    char* ws = (char*)d_ws;
    size_t off = 0;
    auto alloc = [&](size_t bytes) {
        void* p = ws + off;
        off = (off + bytes + 255) & ~(size_t)255;
        return p;
    };
    u16* inp = (u16*)alloc((size_t)N_BONDS * HP * sizeof(u16));   // 128 MB
    u16* msg = (u16*)alloc((size_t)N_BONDS * HP * sizeof(u16));   // 128 MB
    u16* Z   = (u16*)alloc((size_t)N_BONDS * HP * sizeof(u16));   // 128 MB
    u16* ZA  = (u16*)alloc((size_t)N_ATOMS * HP * sizeof(u16));   //  64 MB
    short* WiP = (short*)alloc((size_t)KK_I * NT * 64 * 8 * sizeof(short));
    short* WhP = (short*)alloc((size_t)KK_H * NT * 64 * 8 * sizeof(short));
    short* WoP = (short*)alloc((size_t)KK_O * NT * 64 * 8 * sizeof(short));
    u16* ah = Z;   // Z is dead before k4

    pack_w<<<KK_I * NT, 64, 0, stream>>>(Wi, WiP, BOND_FD, NT, 0);
    pack_w<<<KK_H * NT, 64, 0, stream>>>(Wh, WhP, HIDDEN, NT, 0);
    pack_w<<<KK_O * NT, 64, 0, stream>>>(Wo, WoP, ATOM_FD + HIDDEN, NT, 2);

    k1_input<<<N_BONDS / 64, 256, 0, stream>>>(f_bonds, (const short8v*)WiP, inp);

    // iter 1: msg_implicit = relu(inp), staged inside kz
    kz_gemm<1><<<N_BONDS / 64, 256, 0, stream>>>(inp, (const short8v*)WhP, Z);
    k2_gather<<<N_ATOMS * CH / 256, 256, 0, stream>>>(Z, a2b, ZA);
    ke_update<<<N_BONDS * CH / 256, 256, 0, stream>>>(inp, ZA, Z, b2a, b2revb, msg);

    // iter 2
    kz_gemm<0><<<N_BONDS / 64, 256, 0, stream>>>(msg, (const short8v*)WhP, Z);
    k2_gather<<<N_ATOMS * CH / 256, 256, 0, stream>>>(Z, a2b, ZA);
    ke_update<<<N_BONDS * CH / 256, 256, 0, stream>>>(inp, ZA, Z, b2a, b2revb, msg);

    k2_gather<<<N_ATOMS * CH / 256, 256, 0, stream>>>(msg, a2b, ZA);
    k4_readout<<<(N_ATOMS + 63) / 64, 256, 0, stream>>>(f_atoms, ZA,
                                                        (const short8v*)WoP, bo, ah);
    k5_pool<<<N_MOLS, 320, 0, stream>>>(ah, out);
}

// Round 5
// 822.573 us; speedup vs baseline: 4.2128x; 1.1320x over previous
//
#include <hip/hip_runtime.h>
#include <hip/hip_bf16.h>

#define N_ATOMS 100000
#define N_BONDS 200000
#define MAX_NB 6
#define HIDDEN 300
#define HP 320               // padded hidden: row = 640 B = 40 x 16B chunks
#define CH 40
#define ATOM_FD 133
#define BOND_FD 147
#define N_MOLS 5000
#define APM 20

#define NT 20                // 20*16 = 320 output cols (300 real + 20 zero)
#define KK_I 5               // K=160 >= 147
#define KK_H 10              // K=320 >= 300
#define KK_O 14              // K=448 >= 433

using bf16 = __hip_bfloat16;
typedef __attribute__((ext_vector_type(8))) short short8v;
typedef __attribute__((ext_vector_type(4))) float float4v;
typedef unsigned int u32;
typedef unsigned short u16;

__device__ __forceinline__ float us2f(u16 u) {
    union { u32 i; float f; } v; v.i = ((u32)u) << 16; return v.f;
}
__device__ __forceinline__ u16 f2us(float f) {
    bf16 h = __float2bfloat16(f);
    return *(u16*)&h;
}
__device__ __forceinline__ u32 pack2(float a, float b) {
    return (u32)f2us(a) | ((u32)f2us(b) << 16);
}
__device__ __forceinline__ uint2 pack4(const float4v& a) {
    uint2 o; o.x = pack2(a[0], a[1]); o.y = pack2(a[2], a[3]); return o;
}
__device__ __forceinline__ u32 relu2(u32 u) {
    u32 r = (u & 0x80000000u) ? (u & 0x0000ffffu) : u;
    r = (r & 0x8000u) ? (r & 0xffff0000u) : r;
    return r;
}
__device__ __forceinline__ uint4 relu8(uint4 u) {
    u.x = relu2(u.x); u.y = relu2(u.y); u.z = relu2(u.z); u.w = relu2(u.w);
    return u;
}

// ---------------------------------------------------------------------------
// pack_w: W [Ksrc x 300] fp32 -> bf16 MFMA-B fragments [KK][NT][64][8]
// mode==2 (W_o): K layout is [amsg(0..299) | f_atoms(300..432)].
__global__ __launch_bounds__(64) void pack_w(const float* __restrict__ src,
                                             short* __restrict__ dst,
                                             int Ksrc, int mode) {
    int kk = blockIdx.x / NT, nt = blockIdx.x % NT;
    int lane = threadIdx.x;
    int col = nt * 16 + (lane & 15);
#pragma unroll
    for (int j = 0; j < 8; ++j) {
        int k = kk * 32 + (lane >> 4) * 8 + j;
        float v = 0.f;
        if (k < Ksrc && col < HIDDEN) {
            int krow = k;
            if (mode == 2) krow = (k < HIDDEN) ? (ATOM_FD + k) : (k - HIDDEN);
            v = src[krow * HIDDEN + col];
        }
        dst[(((kk * NT + nt) << 6) + lane) * 8 + j] = (short)f2us(v);
    }
}

// ---------------------------------------------------------------------------
// K1: inp = f_bonds @ W_i. 32 rows/block (20KB LDS -> 8 blocks/CU).
__global__ __launch_bounds__(256) void k1_input(const float* __restrict__ fb,
                                                const short8v* __restrict__ WiP,
                                                u16* __restrict__ inp) {
    __shared__ char sm[32 * 640];
    const int tid = threadIdx.x;
    const long base = (long)blockIdx.x * 32;
#pragma unroll
    for (int it = 0; it < 20; ++it) {
        int i = tid + it * 256;
        int row = i / 160, c = i % 160;
        float v = (c < BOND_FD) ? fb[(base + row) * BOND_FD + c] : 0.f;
        int byte = row * 320 + c * 2;
        *(u16*)(sm + (byte ^ ((row & 7) << 4))) = f2us(v);
    }
    __syncthreads();

    const int lane = tid & 63, wave = tid >> 6;
    const int nt0 = wave * 5;
    const int arow0 = lane & 15, ahi = lane >> 4;
    float4v acc[5][2];
#pragma unroll
    for (int nt = 0; nt < 5; ++nt)
#pragma unroll
        for (int rg = 0; rg < 2; ++rg) acc[nt][rg] = {0.f, 0.f, 0.f, 0.f};
    for (int kk = 0; kk < KK_I; ++kk) {
        short8v a[2];
#pragma unroll
        for (int rg = 0; rg < 2; ++rg) {
            int row = rg * 16 + arow0;
            int byte = row * 320 + kk * 64 + ahi * 16;
            a[rg] = *(const short8v*)(sm + (byte ^ ((row & 7) << 4)));
        }
#pragma unroll
        for (int nt = 0; nt < 5; ++nt) {
            short8v b = WiP[((kk * NT + nt0 + nt) << 6) + lane];
#pragma unroll
            for (int rg = 0; rg < 2; ++rg)   // swapped: acc = C^T fragments
                acc[nt][rg] = __builtin_amdgcn_mfma_f32_16x16x32_bf16(b, a[rg], acc[nt][rg], 0, 0, 0);
        }
    }
    __syncthreads();
#pragma unroll
    for (int nt = 0; nt < 5; ++nt)
#pragma unroll
        for (int rg = 0; rg < 2; ++rg) {
            int row = rg * 16 + arow0;
            int byte = row * 640 + (nt0 + nt) * 32 + ahi * 8;
            *(uint2*)(sm + (byte ^ ((row & 7) << 4))) = pack4(acc[nt][rg]);
        }
    __syncthreads();
#pragma unroll
    for (int it = 0; it < 5; ++it) {
        int id = tid + it * 256;
        int row = id / CH, c = id % CH;
        int byte = row * 640 + c * 16;
        uint4 v = *(const uint4*)(sm + (byte ^ ((row & 7) << 4)));
        ((uint4*)(inp + (base + row) * HP))[c] = v;
    }
}

// ---------------------------------------------------------------------------
// K2G: dst[a] = sum_j act(src[a2b[a][j]]) — flat thread-per-16B-chunk.
template<int RELU>
__global__ __launch_bounds__(256) void k2_gather(const u16* __restrict__ src,
                                                 const int* __restrict__ a2b,
                                                 u16* __restrict__ dst) {
    int id = blockIdx.x * 256 + threadIdx.x;
    int atom = id / CH, c = id % CH;
    const int* nb = a2b + atom * MAX_NB;
    float s0=0,s1=0,s2=0,s3=0,s4=0,s5=0,s6=0,s7=0;
#pragma unroll
    for (int j = 0; j < MAX_NB; ++j) {
        int b = nb[j];
        uint4 u = ((const uint4*)(src + (long)b * HP))[c];
        if (RELU) u = relu8(u);
        s0 += us2f(u.x & 0xffff); s1 += us2f(u.x >> 16);
        s2 += us2f(u.y & 0xffff); s3 += us2f(u.y >> 16);
        s4 += us2f(u.z & 0xffff); s5 += us2f(u.z >> 16);
        s6 += us2f(u.w & 0xffff); s7 += us2f(u.w >> 16);
    }
    uint4 o;
    o.x = pack2(s0, s1); o.y = pack2(s2, s3);
    o.z = pack2(s4, s5); o.w = pack2(s6, s7);
    ((uint4*)(dst + (long)atom * HP))[c] = o;
}

// ---------------------------------------------------------------------------
// KZF: msg_out = relu(inp + (AM[b2a] - act(msgsrc[b2revb])) @ W_h)
// Fused: gather-diff in stage, +inp as MFMA C-init, relu in epilogue.
// 32 rows/block (20KB LDS).
template<int RELUREV>
__global__ __launch_bounds__(256) void kzf_update(const u16* __restrict__ inp,
                                                  const u16* __restrict__ AM,
                                                  const u16* __restrict__ msgsrc,
                                                  const int* __restrict__ b2a,
                                                  const int* __restrict__ b2revb,
                                                  const short8v* __restrict__ WhP,
                                                  u16* __restrict__ msgdst) {
    __shared__ char sm[32 * 640];
    const int tid = threadIdx.x;
    const long base = (long)blockIdx.x * 32;
    const int lane = tid & 63, wave = tid >> 6;
    const int nt0 = wave * 5;
    const int arow0 = lane & 15, ahi = lane >> 4;

    // issue the +inp loads early (consumed as C-init after the barrier)
    uint2 t[5][2];
#pragma unroll
    for (int nt = 0; nt < 5; ++nt)
#pragma unroll
        for (int rg = 0; rg < 2; ++rg)
            t[nt][rg] = *(const uint2*)(inp + (base + rg * 16 + arow0) * HP
                                        + (nt0 + nt) * 16 + ahi * 4);

    // stage: m = AM[b2a[row]] - act(msgsrc[b2revb[row]]) into LDS
#pragma unroll
    for (int it = 0; it < 5; ++it) {
        int i = tid + it * 256;
        int row = i / CH, c = i % CH;
        long b = base + row;
        int ia = b2a[b], ir = b2revb[b];
        uint4 ua = ((const uint4*)(AM + (long)ia * HP))[c];
        uint4 uz = ((const uint4*)(msgsrc + (long)ir * HP))[c];
        if (RELUREV) uz = relu8(uz);
        uint4 o;
#define EL(w) o.w = pack2(us2f(ua.w & 0xffff) - us2f(uz.w & 0xffff), \
                          us2f(ua.w >> 16)    - us2f(uz.w >> 16));
        EL(x) EL(y) EL(z) EL(w)
#undef EL
        int byte = row * 640 + c * 16;
        *(uint4*)(sm + (byte ^ ((row & 7) << 4))) = o;
    }
    __syncthreads();

    float4v acc[5][2];
#pragma unroll
    for (int nt = 0; nt < 5; ++nt)
#pragma unroll
        for (int rg = 0; rg < 2; ++rg) {
            uint2 u = t[nt][rg];
            acc[nt][rg][0] = us2f(u.x & 0xffff);
            acc[nt][rg][1] = us2f(u.x >> 16);
            acc[nt][rg][2] = us2f(u.y & 0xffff);
            acc[nt][rg][3] = us2f(u.y >> 16);
        }
    for (int kk = 0; kk < KK_H; ++kk) {
        short8v a[2];
#pragma unroll
        for (int rg = 0; rg < 2; ++rg) {
            int row = rg * 16 + arow0;
            int byte = row * 640 + kk * 64 + ahi * 16;
            a[rg] = *(const short8v*)(sm + (byte ^ ((row & 7) << 4)));
        }
#pragma unroll
        for (int nt = 0; nt < 5; ++nt) {
            short8v b = WhP[((kk * NT + nt0 + nt) << 6) + lane];
#pragma unroll
            for (int rg = 0; rg < 2; ++rg)
                acc[nt][rg] = __builtin_amdgcn_mfma_f32_16x16x32_bf16(b, a[rg], acc[nt][rg], 0, 0, 0);
        }
    }
    __syncthreads();
#pragma unroll
    for (int nt = 0; nt < 5; ++nt)
#pragma unroll
        for (int rg = 0; rg < 2; ++rg) {
            int row = rg * 16 + arow0;
            float4v v;
#pragma unroll
            for (int q = 0; q < 4; ++q) v[q] = fmaxf(acc[nt][rg][q], 0.f);
            int byte = row * 640 + (nt0 + nt) * 32 + ahi * 8;
            *(uint2*)(sm + (byte ^ ((row & 7) << 4))) = pack4(v);
        }
    __syncthreads();
#pragma unroll
    for (int it = 0; it < 5; ++it) {
        int id = tid + it * 256;
        int row = id / CH, c = id % CH;
        int byte = row * 640 + c * 16;
        uint4 v = *(const uint4*)(sm + (byte ^ ((row & 7) << 4)));
        ((uint4*)(msgdst + (base + row) * HP))[c] = v;
    }
}

// ---------------------------------------------------------------------------
// K4: fused readout + pool. 80 atoms = 4 molecules per block.
// ah = relu([amsg | f_atoms] @ WoP + b_o); out[mol] = mean over 20 atoms.
__global__ __launch_bounds__(256) void k4_readout(const float* __restrict__ fa,
                                                  const u16* __restrict__ AM,
                                                  const short8v* __restrict__ WoP,
                                                  const float* __restrict__ bo,
                                                  float* __restrict__ out) {
    __shared__ char sm[80 * 896];
    const int tid = threadIdx.x;
    const long base = (long)blockIdx.x * 80;
    for (int i = tid; i < 80 * 75; i += 256) {   // amsg cols 0..299
        int row = i / 75, c = i % 75;
        uint2 o = ((const uint2*)(AM + (base + row) * HP))[c];
        int byte = row * 896 + c * 8;
        *(uint2*)(sm + (byte ^ ((row & 7) << 4))) = o;
    }
    for (int i = tid; i < 80 * 148; i += 256) {  // f_atoms cols 300..432 + pad
        int row = i / 148, c2 = i % 148;
        float v = (c2 < ATOM_FD) ? fa[(base + row) * ATOM_FD + c2] : 0.f;
        int byte = row * 896 + (HIDDEN + c2) * 2;
        *(u16*)(sm + (byte ^ ((row & 7) << 4))) = f2us(v);
    }
    __syncthreads();

    const int lane = tid & 63, wave = tid >> 6;
    const int nt0 = wave * 5;
    const int arow0 = lane & 15, ahi = lane >> 4;
    float4v acc[5][5];
#pragma unroll
    for (int nt = 0; nt < 5; ++nt)
#pragma unroll
        for (int rg = 0; rg < 5; ++rg) acc[nt][rg] = {0.f, 0.f, 0.f, 0.f};
    for (int kk = 0; kk < KK_O; ++kk) {
        short8v a[5];
#pragma unroll
        for (int rg = 0; rg < 5; ++rg) {
            int row = rg * 16 + arow0;
            int byte = row * 896 + kk * 64 + ahi * 16;
            a[rg] = *(const short8v*)(sm + (byte ^ ((row & 7) << 4)));
        }
#pragma unroll
        for (int nt = 0; nt < 5; ++nt) {
            short8v b = WoP[((kk * NT + nt0 + nt) << 6) + lane];
#pragma unroll
            for (int rg = 0; rg < 5; ++rg)
                acc[nt][rg] = __builtin_amdgcn_mfma_f32_16x16x32_bf16(b, a[rg], acc[nt][rg], 0, 0, 0);
        }
    }
    __syncthreads();
#pragma unroll
    for (int nt = 0; nt < 5; ++nt) {
        int colb = (nt0 + nt) * 16 + ahi * 4;
        float bias[4];
#pragma unroll
        for (int q = 0; q < 4; ++q)
            bias[q] = (colb + q < HIDDEN) ? bo[colb + q] : 0.f;
#pragma unroll
        for (int rg = 0; rg < 5; ++rg) {
            int row = rg * 16 + arow0;
            float4v v;
#pragma unroll
            for (int q = 0; q < 4; ++q) v[q] = fmaxf(acc[nt][rg][q] + bias[q], 0.f);
            int byte = row * 640 + (nt0 + nt) * 32 + ahi * 8;
            *(uint2*)(sm + (byte ^ ((row & 7) << 4))) = pack4(v);
        }
    }
    __syncthreads();
    // pool: 4 molecules x 300 cols, mean over 20 rows each
    for (int idx = tid; idx < 4 * HIDDEN; idx += 256) {
        int m = idx / HIDDEN, col = idx % HIDDEN;
        float s = 0.f;
#pragma unroll
        for (int r = 0; r < APM; ++r) {
            int row = m * APM + r;
            int byte = row * 640 + col * 2;
            s += us2f(*(const u16*)(sm + (byte ^ ((row & 7) << 4))));
        }
        out[((long)blockIdx.x * 4 + m) * HIDDEN + col] = s * (1.f / APM);
    }
}

// ---------------------------------------------------------------------------
extern "C" void kernel_launch(void* const* d_in, const int* in_sizes, int n_in,
                              void* d_out, int out_size, void* d_ws, size_t ws_size,
                              hipStream_t stream) {
    const float* f_atoms = (const float*)d_in[0];
    const float* f_bonds = (const float*)d_in[1];
    const int* a2b = (const int*)d_in[2];
    const int* b2a = (const int*)d_in[3];
    const int* b2revb = (const int*)d_in[4];
    const float* Wi = (const float*)d_in[6];
    const float* Wh = (const float*)d_in[7];
    const float* Wo = (const float*)d_in[8];
    const float* bo = (const float*)d_in[9];
    float* out = (float*)d_out;

    char* ws = (char*)d_ws;
    size_t off = 0;
    auto alloc = [&](size_t bytes) {
        void* p = ws + off;
        off = (off + bytes + 255) & ~(size_t)255;
        return p;
    };
    u16* inp  = (u16*)alloc((size_t)N_BONDS * HP * sizeof(u16));   // 128 MB
    u16* msgA = (u16*)alloc((size_t)N_BONDS * HP * sizeof(u16));   // 128 MB
    u16* msgB = (u16*)alloc((size_t)N_BONDS * HP * sizeof(u16));   // 128 MB
    u16* AM   = (u16*)alloc((size_t)N_ATOMS * HP * sizeof(u16));   //  64 MB
    short* WiP = (short*)alloc((size_t)KK_I * NT * 64 * 8 * sizeof(short));
    short* WhP = (short*)alloc((size_t)KK_H * NT * 64 * 8 * sizeof(short));
    short* WoP = (short*)alloc((size_t)KK_O * NT * 64 * 8 * sizeof(short));

    pack_w<<<KK_I * NT, 64, 0, stream>>>(Wi, WiP, BOND_FD, 0);
    pack_w<<<KK_H * NT, 64, 0, stream>>>(Wh, WhP, HIDDEN, 0);
    pack_w<<<KK_O * NT, 64, 0, stream>>>(Wo, WoP, ATOM_FD + HIDDEN, 2);

    k1_input<<<N_BONDS / 32, 256, 0, stream>>>(f_bonds, (const short8v*)WiP, inp);

    // iter 1: msg0 = relu(inp) applied on the fly
    k2_gather<1><<<N_ATOMS * CH / 256, 256, 0, stream>>>(inp, a2b, AM);
    kzf_update<1><<<N_BONDS / 32, 256, 0, stream>>>(inp, AM, inp, b2a, b2revb,
                                                    (const short8v*)WhP, msgA);
    // iter 2
    k2_gather<0><<<N_ATOMS * CH / 256, 256, 0, stream>>>(msgA, a2b, AM);
    kzf_update<0><<<N_BONDS / 32, 256, 0, stream>>>(inp, AM, msgA, b2a, b2revb,
                                                    (const short8v*)WhP, msgB);
    // readout + pool
    k2_gather<0><<<N_ATOMS * CH / 256, 256, 0, stream>>>(msgB, a2b, AM);
    k4_readout<<<N_ATOMS / 80, 256, 0, stream>>>(f_atoms, AM,
                                                 (const short8v*)WoP, bo, out);
}